// Round 1
// baseline (6389.308 us; speedup 1.0000x reference)
//
#include <hip/hip_runtime.h>
#include <hip/hip_fp16.h>

#define SEQ  1000
#define IDIM 900
#define H    4096

// LDS carve-up for esn_recurrent (row-ownership: 16 full rows per block,
// 4 waves x 4 rows, XOR-swizzled fp16 pairs):
//   w2 : uint[16][2048] fp16-pair weights (swizzled)      = 131072 B
//   s2 : uint[2][2048]  s[t] fp16 pairs (double-buffered) =  16384 B
#define LDS_BYTES (131072 + 16384)

typedef _Float16 h2_t __attribute__((ext_vector_type(2)));

__device__ __forceinline__ float fdot2(unsigned a, unsigned b, float c) {
#if __has_builtin(__builtin_amdgcn_fdot2)
    return __builtin_amdgcn_fdot2(__builtin_bit_cast(h2_t, a),
                                  __builtin_bit_cast(h2_t, b), c, false);
#else
    h2_t ha = __builtin_bit_cast(h2_t, a);
    h2_t hb = __builtin_bit_cast(h2_t, b);
    return c + (float)ha.x * (float)hb.x + (float)ha.y * (float)hb.y;
#endif
}

__device__ __forceinline__ float tanh_fast(float x) {
    float ax = __builtin_fabsf(x);
    float e  = __expf(-2.0f * ax);
    float t  = (1.0f - e) / (1.0f + e);
    return __builtin_copysignf(t, x);
}

// Bank-conflict-free swizzle on dword indices within a 2048-dword row:
// dword d = 32*l + 4*c + j  (l = lane block, c = 16B chunk 0..7, j = dword).
// XOR the chunk index with (l&7): every 8-lane group then covers all 32
// banks exactly once per b128 access -> exact 8-cycle floor, 0 conflicts.
// Row offsets are multiples of 2048 dwords (bit 11+), so applying swz to a
// row-global index only permutes bits [4:2] within the row. Writers
// (staging + poll) and readers use the same involution.
__device__ __forceinline__ int swz(int d) { return d ^ (((d >> 5) & 7) << 2); }

// ---------------------------------------------------------------------------
// Persistent recurrent kernel, round-8: WAVE-COMPLETE ROWS.
// 256 blocks x 256 threads (4 waves), cooperative. Block B owns rows
// [16B,+16); wave w owns rows 4w..4w+3 across ALL 4096 cols (64 cols/lane).
// A 6-stage __shfl_xor butterfly leaves every lane holding all 4 complete
// row sums -> tanh + tagged publish happen straight out of registers with
// ZERO barriers in the tail (round 7 had 3 syncthreads + 2 LDS round-trips
// there). s2 is double-buffered so the single post-poll __syncthreads is
// sufficient: a fast wave at step t+1 writes s2[(t+1)&1] while a slow wave
// still reads s2[t&1]. w2/s2 are XOR-swizzled (round 7: 1.8e8 conflict
// cycles from 16-way b128 conflicts).
// Publish protocol unchanged (proven): 4 slots x 2048 tagged words
// {u32 tag = t+2, 2 x fp16}; thread t polls the 8 words of producer block t.
// ---------------------------------------------------------------------------
__global__ __launch_bounds__(256, 1) void esn_recurrent(
    const float* __restrict__ Whh,            // H*H row-major fp32
    const float* __restrict__ pre_in,         // SEQ*H = X @ W_ih^T  (ws)
    float*       __restrict__ states,         // SEQ*H (inside d_out)
    unsigned long long* __restrict__ part)    // 4*2048 tagged words (d_out scratch)
{
    extern __shared__ char smem[];
    unsigned* w2 = (unsigned*)smem;                 // [16*2048] swizzled
    unsigned* s2 = (unsigned*)(smem + 131072);      // [2*2048]  swizzled

    const int B    = blockIdx.x;       // owns rows [16B, +16)
    const int tid  = threadIdx.x;
    const int wave = tid >> 6;         // 0..3, owns rows 4w..4w+3
    const int lane = tid & 63;

    // ---- prologue: publish s[0] for my rows (wave 0, no barriers) ----
    if (wave == 0) {
        float s0 = 0.f;
        if (lane < 16) {
            s0 = tanh_fast(pre_in[(B << 4) + lane]);
            states[(B << 4) + lane] = s0;
        }
        float a = __shfl(s0, lane << 1);
        float b = __shfl(s0, (lane << 1) + 1);
        if (lane < 8) {
            __half2 p = __floats2half2_rn(a, b);
            unsigned long long wrd = (1ull << 32)
                                   | (unsigned long long)(*(unsigned*)&p);
            __hip_atomic_store(part + (B << 3) + lane, wrd,
                               __ATOMIC_RELAXED, __HIP_MEMORY_SCOPE_AGENT);
        }
    }

    // ---- stage my 16 rows of W_hh into swizzled LDS fp16 (once) ----
    {
        const float* wsrc = Whh + ((size_t)(B << 4)) * H;
        #pragma unroll
        for (int r = 0; r < 16; ++r) {
            const float* rp = wsrc + ((size_t)r << 12) + (tid << 4);
            float4 f0 = *(const float4*)(rp);
            float4 f1 = *(const float4*)(rp + 4);
            float4 f2 = *(const float4*)(rp + 8);
            float4 f3 = *(const float4*)(rp + 12);
            uint4 lo, hi;
            __half2 p;
            p = __floats2half2_rn(f0.x, f0.y); lo.x = *(unsigned*)&p;
            p = __floats2half2_rn(f0.z, f0.w); lo.y = *(unsigned*)&p;
            p = __floats2half2_rn(f1.x, f1.y); lo.z = *(unsigned*)&p;
            p = __floats2half2_rn(f1.z, f1.w); lo.w = *(unsigned*)&p;
            p = __floats2half2_rn(f2.x, f2.y); hi.x = *(unsigned*)&p;
            p = __floats2half2_rn(f2.z, f2.w); hi.y = *(unsigned*)&p;
            p = __floats2half2_rn(f3.x, f3.y); hi.z = *(unsigned*)&p;
            p = __floats2half2_rn(f3.z, f3.w); hi.w = *(unsigned*)&p;
            const int d = (r << 11) + (tid << 3);
            *(uint4*)(w2 + swz(d))     = lo;
            *(uint4*)(w2 + swz(d + 4)) = hi;
        }
    }
    __syncthreads();

    const int row0 = (B << 4) + (wave << 2);

    for (int t = 0; t < SEQ - 1; ++t) {
        // prefetch pre_in[t+1] for my 4 rows (issued before the poll)
        float pv = pre_in[(size_t)(t + 1) * H + row0 + (lane & 3)];

        // ---- A. poll s[t] (slot t&3, tag t+1); thread polls 8 words,
        //         all produced by block `tid` (one 64 B line) ----
        unsigned long long v[8];
        {
            const unsigned long long* pb = part + ((size_t)(t & 3) << 11) + (tid << 3);
            const unsigned want = (unsigned)(t + 1);
            for (;;) {
                #pragma unroll
                for (int k = 0; k < 8; ++k)
                    v[k] = __hip_atomic_load(pb + k, __ATOMIC_RELAXED,
                                             __HIP_MEMORY_SCOPE_AGENT);
                unsigned m = 0;
                #pragma unroll
                for (int k = 0; k < 8; ++k) m |= ((unsigned)(v[k] >> 32)) ^ want;
                if (m == 0) break;
                __builtin_amdgcn_s_sleep(1);
            }
        }
        unsigned* sb = s2 + ((t & 1) << 11);
        {
            uint4 lo, hi;
            lo.x = (unsigned)v[0]; lo.y = (unsigned)v[1];
            lo.z = (unsigned)v[2]; lo.w = (unsigned)v[3];
            hi.x = (unsigned)v[4]; hi.y = (unsigned)v[5];
            hi.z = (unsigned)v[6]; hi.w = (unsigned)v[7];
            *(uint4*)(sb + swz(tid << 3))       = lo;
            *(uint4*)(sb + swz((tid << 3) + 4)) = hi;
        }
        __syncthreads();   // the ONLY barrier per step

        // ---- B. compute rows 4w..4w+3 over cols [64*lane, +64) ----
        uint4 sv[8];
        #pragma unroll
        for (int c = 0; c < 8; ++c)
            sv[c] = *(const uint4*)(sb + (lane << 5) + ((c ^ (lane & 7)) << 2));

        float acc[4] = {0.f, 0.f, 0.f, 0.f};
        #pragma unroll
        for (int q = 0; q < 4; ++q) {
            const unsigned* wr = w2 + (((wave << 2) + q) << 11);
            #pragma unroll
            for (int c = 0; c < 8; ++c) {
                uint4 wv = *(const uint4*)(wr + (lane << 5) + ((c ^ (lane & 7)) << 2));
                acc[q] = fdot2(wv.x, sv[c].x, acc[q]);
                acc[q] = fdot2(wv.y, sv[c].y, acc[q]);
                acc[q] = fdot2(wv.z, sv[c].z, acc[q]);
                acc[q] = fdot2(wv.w, sv[c].w, acc[q]);
            }
        }

        // 64-lane butterfly: all lanes end with all 4 complete row sums
        #pragma unroll
        for (int off = 32; off; off >>= 1) {
            #pragma unroll
            for (int q = 0; q < 4; ++q) acc[q] += __shfl_xor(acc[q], off);
        }

        // ---- C. tail, zero barriers: tanh + store + publish from regs ----
        float av = (lane & 2) ? ((lane & 1) ? acc[3] : acc[2])
                              : ((lane & 1) ? acc[1] : acc[0]);
        float sf = tanh_fast(av + pv);
        if (lane < 4) states[(size_t)(t + 1) * H + row0 + lane] = sf;
        float a = __shfl(sf, lane << 1);
        float b = __shfl(sf, (lane << 1) + 1);
        if (lane < 2) {
            __half2 p = __floats2half2_rn(a, b);
            unsigned long long wrd = ((unsigned long long)(unsigned)(t + 2) << 32)
                                   | (unsigned long long)(*(unsigned*)&p);
            __hip_atomic_store(part + ((size_t)((t + 1) & 3) << 11)
                                    + (B << 3) + (wave << 1) + lane,
                               wrd, __ATOMIC_RELAXED, __HIP_MEMORY_SCOPE_AGENT);
        }
    }
}

// ---------------------------------------------------------------------------
// Generic fp32 tiled GEMM:  C[MxN] = A[MxK] * B[NxK]^T   (both row-major)
// mode 0: A plain (lda). mode 1: virtual ext row t: [1, X[t], S[t]].
// ---------------------------------------------------------------------------
#define BM 64
#define BN 64
#define BK 32

__global__ __launch_bounds__(256) void gemm_abt(
    const float* __restrict__ A, int lda,
    const float* __restrict__ B, int ldb,
    float*       __restrict__ C, int ldc,
    int Mdim, int N, int K, int mode,
    const float* __restrict__ X, const float* __restrict__ S)
{
    __shared__ float As[BK][BM + 1];
    __shared__ float Bs[BK][BN + 1];

    const int tid = threadIdx.x;
    const int n0  = blockIdx.x * BN;
    const int m0  = blockIdx.y * BM;
    const int tx  = tid & 15;
    const int ty  = tid >> 4;

    float c[4][4] = {};

    for (int k0 = 0; k0 < K; k0 += BK) {
        #pragma unroll
        for (int p = 0; p < 8; ++p) {
            const int idx = tid + p * 256;
            const int mm  = idx >> 5;
            const int kk  = idx & 31;
            const int gk  = k0 + kk;

            float av = 0.f;
            const int gm = m0 + mm;
            if (gm < Mdim && gk < K) {
                if (mode == 0) {
                    av = A[(size_t)gm * lda + gk];
                } else {
                    if (gk == 0)          av = 1.0f;
                    else if (gk <= IDIM)  av = X[(size_t)gm * IDIM + (gk - 1)];
                    else                  av = S[(size_t)gm * H + (gk - 1 - IDIM)];
                }
            }
            As[kk][mm] = av;

            float bv = 0.f;
            const int gn = n0 + mm;
            if (gn < N && gk < K) bv = B[(size_t)gn * ldb + gk];
            Bs[kk][mm] = bv;
        }
        __syncthreads();

        #pragma unroll
        for (int kk = 0; kk < BK; ++kk) {
            float a[4], bb[4];
            #pragma unroll
            for (int i = 0; i < 4; ++i) a[i]  = As[kk][ty * 4 + i];
            #pragma unroll
            for (int j = 0; j < 4; ++j) bb[j] = Bs[kk][tx * 4 + j];
            #pragma unroll
            for (int i = 0; i < 4; ++i)
                #pragma unroll
                for (int j = 0; j < 4; ++j)
                    c[i][j] += a[i] * bb[j];
        }
        __syncthreads();
    }

    #pragma unroll
    for (int i = 0; i < 4; ++i) {
        const int gm = m0 + ty * 4 + i;
        if (gm >= Mdim) continue;
        #pragma unroll
        for (int j = 0; j < 4; ++j) {
            const int gn = n0 + tx * 4 + j;
            if (gn < N) C[(size_t)gm * ldc + gn] = c[i][j];
        }
    }
}

// ---------------------------------------------------------------------------
// Launcher
// ---------------------------------------------------------------------------
extern "C" void kernel_launch(void* const* d_in, const int* in_sizes, int n_in,
                              void* d_out, int out_size, void* d_ws, size_t ws_size,
                              hipStream_t stream) {
    const float* inputs = (const float*)d_in[0];
    // d_in[1] = initial state (zeros) — folded out
    const float* W_ih   = (const float*)d_in[2];
    const float* W_hh   = (const float*)d_in[3];
    const float* W_out  = (const float*)d_in[4];

    float* out    = (float*)d_out;                 // SEQ*IDIM
    float* states = out + (size_t)SEQ * IDIM;      // SEQ*H

    float* pre_in = (float*)d_ws;                  // SEQ*H fp32 (16.4 MB)

    // Tagged s-broadcast scratch in the outputs region of d_out (overwritten
    // by phase 2): 4 slots * 2048 words * 8 B = 64 KB. Harness 0xAA poison
    // gives tag 0xAAAAAAAA, never equal to a live tag (1..1000).
    unsigned long long* part = (unsigned long long*)out;

    (void)hipFuncSetAttribute((const void*)esn_recurrent,
                              hipFuncAttributeMaxDynamicSharedMemorySize,
                              LDS_BYTES);

    // Phase 0: pre_in[t][r] = sum_i X[t][i] * W_ih[r][i]
    gemm_abt<<<dim3(H / BN, (SEQ + BM - 1) / BM), 256, 0, stream>>>(
        inputs, IDIM, W_ih, IDIM, pre_in, H, SEQ, H, IDIM, 0, nullptr, nullptr);

    // Phase 1: persistent sequential recurrence (256 blocks x 256 threads)
    {
        const float* whh_p = W_hh;
        const float* pin_p = pre_in;
        float* st_p = states;
        unsigned long long* part_p = part;
        void* args[] = { (void*)&whh_p, (void*)&pin_p, (void*)&st_p, (void*)&part_p };
        hipLaunchCooperativeKernel((const void*)esn_recurrent,
                                   dim3(256), dim3(256), args, LDS_BYTES, stream);
    }

    // Phase 2: outputs[t][i] = sum_k ext[t][k] * W_out[i][k]
    gemm_abt<<<dim3((IDIM + BN - 1) / BN, (SEQ + BM - 1) / BM), 256, 0, stream>>>(
        nullptr, 0, W_out, 1 + IDIM + H, out, IDIM,
        SEQ, IDIM, 1 + IDIM + H, 1, inputs, states);
}

// Round 2
// 4373.684 us; speedup vs baseline: 1.4609x; 1.4609x over previous
//
#include <hip/hip_runtime.h>
#include <hip/hip_fp16.h>

#define SEQ  1000
#define IDIM 900
#define H    4096

// LDS carve-up for esn_recurrent (W_hh lives in REGISTERS now):
//   s2   : uint[2][2048]  s[t] fp16 pairs, double-buffered = 16384 B
//   redf : float[16][5]   per-(row,colquad) partials       =   320 B
#define LDS_BYTES (16384 + 320)

typedef _Float16 h2_t __attribute__((ext_vector_type(2)));

__device__ __forceinline__ float fdot2(unsigned a, unsigned b, float c) {
#if __has_builtin(__builtin_amdgcn_fdot2)
    return __builtin_amdgcn_fdot2(__builtin_bit_cast(h2_t, a),
                                  __builtin_bit_cast(h2_t, b), c, false);
#else
    h2_t ha = __builtin_bit_cast(h2_t, a);
    h2_t hb = __builtin_bit_cast(h2_t, b);
    return c + (float)ha.x * (float)hb.x + (float)ha.y * (float)hb.y;
#endif
}

__device__ __forceinline__ float tanh_fast(float x) {
    float ax = __builtin_fabsf(x);
    float e  = __expf(-2.0f * ax);
    float t  = (1.0f - e) / (1.0f + e);
    return __builtin_copysignf(t, x);
}

// Bank swizzle on s2 dword indices: XOR bits [4:2] with bits [7:5].
// Writer (b64 at d=2*tid) stays 8B-aligned/contiguous (bits [1:0] untouched);
// reader (b128 at d=512*qd+8*lane) stays 16B-aligned/contiguous. Reader
// banks: quad = (2*(lane&3) | j>>2) ^ ((lane>>2)&7) -> each bank hit exactly
// 8x per wave-b128 = conflict-free floor. Writer: each 16-lane subgroup
// covers all 32 banks once -> 4x floor, conflict-free.
__device__ __forceinline__ int swz2(int d) { return d ^ (((d >> 5) & 7) << 2); }

__device__ __forceinline__ uint4 pack8(float4 f0, float4 f1) {
    __half2 p; uint4 u;
    p = __floats2half2_rn(f0.x, f0.y); u.x = *(unsigned*)&p;
    p = __floats2half2_rn(f0.z, f0.w); u.y = *(unsigned*)&p;
    p = __floats2half2_rn(f1.x, f1.y); u.z = *(unsigned*)&p;
    p = __floats2half2_rn(f1.z, f1.w); u.w = *(unsigned*)&p;
    return u;
}

// ---------------------------------------------------------------------------
// Persistent recurrent kernel, round-9: W_hh IN REGISTERS.
// 256 blocks x 1024 threads (16 waves = 4/SIMD for latency hiding; round-8's
// 1-wave/SIMD config exposed all LDS latency and regressed 44%).
// Block B owns rows [16B,+16). Wave (h=wave>>2, qd=wave&3) computes rows
// 4h..4h+3 over col-quad qd; lane owns 16 cols -> its 4x16 W_hh patch is
// 64 fp16 = 8 uint4 = 32 VGPRs, loaded ONCE from HBM. Per-step LDS is now
// only: 1 b64 s2-write + 2 b128 s2-reads (swizzled, conflict-free) + 7
// shuffles (merged butterfly: stage1 folds acc0/1 + acc2/3 by lane parity,
// stage2 folds again -> lane l carries class l&3; then 4 xor stages).
// Round 7 re-read 128 KB of w2 from LDS every step (~2600 cy + 1.8e8
// conflict cycles total) - all gone.
// Tail: rows 0..15 all live in wave 0 -> finalize + shfl-pack + publish with
// no sfin LDS round-trip. 2 barriers/step (was 3).
// Publish protocol unchanged (proven): 4 slots x 2048 tagged words
// {u32 tag = t+2, 2 x fp16}; thread polls words 2tid,2tid+1; double-buffered
// s2 makes the single post-poll barrier + post-redf barrier sufficient.
// ---------------------------------------------------------------------------
__global__ __launch_bounds__(1024, 4) void esn_recurrent(
    const float* __restrict__ Whh,            // H*H row-major fp32
    const float* __restrict__ pre_in,         // SEQ*H = X @ W_ih^T  (ws)
    float*       __restrict__ states,         // SEQ*H (inside d_out)
    unsigned long long* __restrict__ part)    // 4*2048 tagged words (d_out scratch)
{
    extern __shared__ char smem[];
    unsigned* s2   = (unsigned*)smem;               // [2][2048] swizzled
    float*    redf = (float*)(smem + 16384);        // [16][5]

    const int B    = blockIdx.x;       // owns rows [16B, +16)
    const int tid  = threadIdx.x;
    const int wave = tid >> 6;         // 0..15
    const int lane = tid & 63;
    const int h    = wave >> 2;        // row quad: rows 4h..4h+3 (of my 16)
    const int qd   = wave & 3;         // col quad: cols [1024qd, +1024)

    // ---- prologue first: publish s[0] for my rows (gates other blocks) ----
    if (wave == 0) {
        float s0 = 0.f;
        if (lane < 16) {
            s0 = tanh_fast(pre_in[(B << 4) + lane]);
            states[(B << 4) + lane] = s0;
        }
        float a = __shfl(s0, lane << 1);
        float b = __shfl(s0, (lane << 1) + 1);
        if (lane < 8) {
            __half2 p = __floats2half2_rn(a, b);
            unsigned long long wrd = (1ull << 32)
                                   | (unsigned long long)(*(unsigned*)&p);
            __hip_atomic_store(part + (B << 3) + lane, wrd,
                               __ATOMIC_RELAXED, __HIP_MEMORY_SCOPE_AGENT);
        }
    }

    // ---- load my 4x16 W_hh patch into registers (fp16 pairs, once) ----
    // Latency overlaps with the first poll spin (first use is after barrier A).
    uint4 wa0, wb0, wa1, wb1, wa2, wb2, wa3, wb3;
    {
        const float* wsrc = Whh + ((size_t)((B << 4) + (h << 2))) * H
                          + (qd << 10) + (lane << 4);
        const float4* r0 = (const float4*)(wsrc);
        const float4* r1 = (const float4*)(wsrc + H);
        const float4* r2 = (const float4*)(wsrc + 2 * H);
        const float4* r3 = (const float4*)(wsrc + 3 * H);
        wa0 = pack8(r0[0], r0[1]); wb0 = pack8(r0[2], r0[3]);
        wa1 = pack8(r1[0], r1[1]); wb1 = pack8(r1[2], r1[3]);
        wa2 = pack8(r2[0], r2[1]); wb2 = pack8(r2[2], r2[3]);
        wa3 = pack8(r3[0], r3[1]); wb3 = pack8(r3[2], r3[3]);
    }

    for (int t = 0; t < SEQ - 1; ++t) {
        // prefetch pre_in[t+1] for my rows (issued before the poll)
        float pv = 0.f;
        if (tid < 16) pv = pre_in[(size_t)(t + 1) * H + (B << 4) + tid];

        // ---- A. poll s[t] (slot t&3, tag t+1); thread owns words 2tid,2tid+1 ----
        {
            const unsigned long long* pb = part + ((size_t)(t & 3) << 11) + (tid << 1);
            const unsigned want = (unsigned)(t + 1);
            unsigned long long v0, v1;
            for (;;) {
                v0 = __hip_atomic_load(pb,     __ATOMIC_RELAXED, __HIP_MEMORY_SCOPE_AGENT);
                v1 = __hip_atomic_load(pb + 1, __ATOMIC_RELAXED, __HIP_MEMORY_SCOPE_AGENT);
                if ((unsigned)(v0 >> 32) == want && (unsigned)(v1 >> 32) == want) break;
                __builtin_amdgcn_s_sleep(1);
            }
            uint2 w; w.x = (unsigned)v0; w.y = (unsigned)v1;
            *(uint2*)(s2 + ((t & 1) << 11) + swz2(tid << 1)) = w;
        }
        __syncthreads();   // barrier A

        // ---- B. compute rows 4h..4h+3 x cols [1024qd + 16*lane, +16) ----
        const unsigned* sb = s2 + ((t & 1) << 11);
        const int cb = (qd << 9) + (lane << 3);
        uint4 sa = *(const uint4*)(sb + swz2(cb));
        uint4 sc = *(const uint4*)(sb + swz2(cb + 4));

        float a0 = 0.f, a1 = 0.f, a2 = 0.f, a3 = 0.f;
        a0 = fdot2(wa0.x, sa.x, a0); a0 = fdot2(wa0.y, sa.y, a0);
        a0 = fdot2(wa0.z, sa.z, a0); a0 = fdot2(wa0.w, sa.w, a0);
        a0 = fdot2(wb0.x, sc.x, a0); a0 = fdot2(wb0.y, sc.y, a0);
        a0 = fdot2(wb0.z, sc.z, a0); a0 = fdot2(wb0.w, sc.w, a0);
        a1 = fdot2(wa1.x, sa.x, a1); a1 = fdot2(wa1.y, sa.y, a1);
        a1 = fdot2(wa1.z, sa.z, a1); a1 = fdot2(wa1.w, sa.w, a1);
        a1 = fdot2(wb1.x, sc.x, a1); a1 = fdot2(wb1.y, sc.y, a1);
        a1 = fdot2(wb1.z, sc.z, a1); a1 = fdot2(wb1.w, sc.w, a1);
        a2 = fdot2(wa2.x, sa.x, a2); a2 = fdot2(wa2.y, sa.y, a2);
        a2 = fdot2(wa2.z, sa.z, a2); a2 = fdot2(wa2.w, sa.w, a2);
        a2 = fdot2(wb2.x, sc.x, a2); a2 = fdot2(wb2.y, sc.y, a2);
        a2 = fdot2(wb2.z, sc.z, a2); a2 = fdot2(wb2.w, sc.w, a2);
        a3 = fdot2(wa3.x, sa.x, a3); a3 = fdot2(wa3.y, sa.y, a3);
        a3 = fdot2(wa3.z, sa.z, a3); a3 = fdot2(wa3.w, sa.w, a3);
        a3 = fdot2(wb3.x, sc.x, a3); a3 = fdot2(wb3.y, sc.y, a3);
        a3 = fdot2(wb3.z, sc.z, a3); a3 = fdot2(wb3.w, sc.w, a3);

        // ---- merged butterfly: 7 shuffles instead of 24 ----
        // stage 1 (off 1): fold acc0/acc1 and acc2/acc3 by lane parity
        float y0 = (lane & 1) ? a0 : a1;   // send
        float x  = (lane & 1) ? a1 : a0;   // keep
        x += __shfl_xor(y0, 1);
        float y1 = (lane & 1) ? a2 : a3;
        float z  = (lane & 1) ? a3 : a2;
        z += __shfl_xor(y1, 1);
        // stage 2 (off 2): fold x/z -> lane l carries class (l&3)
        float y2 = (lane & 2) ? x : z;
        float u  = (lane & 2) ? z : x;
        u += __shfl_xor(y2, 2);
        // stages 3..6: plain reduction within class
        u += __shfl_xor(u, 4);
        u += __shfl_xor(u, 8);
        u += __shfl_xor(u, 16);
        u += __shfl_xor(u, 32);
        // lane l (l<4) now holds the full col-quad partial for row 4h+l

        if (lane < 4) redf[((h << 2) + lane) * 5 + qd] = u;
        __syncthreads();   // barrier B

        // ---- C. finalize (wave 0 only; rows 0..15 == lanes 0..15) ----
        if (wave == 0) {
            float sf = 0.f;
            if (lane < 16) {
                const float* rf = redf + lane * 5;
                sf = tanh_fast(rf[0] + rf[1] + rf[2] + rf[3] + pv);
                states[(size_t)(t + 1) * H + (B << 4) + lane] = sf;
            }
            float a = __shfl(sf, lane << 1);
            float b = __shfl(sf, (lane << 1) + 1);
            if (lane < 8) {
                __half2 p = __floats2half2_rn(a, b);
                unsigned long long wrd = ((unsigned long long)(unsigned)(t + 2) << 32)
                                       | (unsigned long long)(*(unsigned*)&p);
                __hip_atomic_store(part + ((size_t)((t + 1) & 3) << 11) + (B << 3) + lane,
                                   wrd, __ATOMIC_RELAXED, __HIP_MEMORY_SCOPE_AGENT);
            }
        }
        // next step's barrier A protects redf reuse; s2 is double-buffered
    }
}

// ---------------------------------------------------------------------------
// Generic fp32 tiled GEMM:  C[MxN] = A[MxK] * B[NxK]^T   (both row-major)
// mode 0: A plain (lda). mode 1: virtual ext row t: [1, X[t], S[t]].
// ---------------------------------------------------------------------------
#define BM 64
#define BN 64
#define BK 32

__global__ __launch_bounds__(256) void gemm_abt(
    const float* __restrict__ A, int lda,
    const float* __restrict__ B, int ldb,
    float*       __restrict__ C, int ldc,
    int Mdim, int N, int K, int mode,
    const float* __restrict__ X, const float* __restrict__ S)
{
    __shared__ float As[BK][BM + 1];
    __shared__ float Bs[BK][BN + 1];

    const int tid = threadIdx.x;
    const int n0  = blockIdx.x * BN;
    const int m0  = blockIdx.y * BM;
    const int tx  = tid & 15;
    const int ty  = tid >> 4;

    float c[4][4] = {};

    for (int k0 = 0; k0 < K; k0 += BK) {
        #pragma unroll
        for (int p = 0; p < 8; ++p) {
            const int idx = tid + p * 256;
            const int mm  = idx >> 5;
            const int kk  = idx & 31;
            const int gk  = k0 + kk;

            float av = 0.f;
            const int gm = m0 + mm;
            if (gm < Mdim && gk < K) {
                if (mode == 0) {
                    av = A[(size_t)gm * lda + gk];
                } else {
                    if (gk == 0)          av = 1.0f;
                    else if (gk <= IDIM)  av = X[(size_t)gm * IDIM + (gk - 1)];
                    else                  av = S[(size_t)gm * H + (gk - 1 - IDIM)];
                }
            }
            As[kk][mm] = av;

            float bv = 0.f;
            const int gn = n0 + mm;
            if (gn < N && gk < K) bv = B[(size_t)gn * ldb + gk];
            Bs[kk][mm] = bv;
        }
        __syncthreads();

        #pragma unroll
        for (int kk = 0; kk < BK; ++kk) {
            float a[4], bb[4];
            #pragma unroll
            for (int i = 0; i < 4; ++i) a[i]  = As[kk][ty * 4 + i];
            #pragma unroll
            for (int j = 0; j < 4; ++j) bb[j] = Bs[kk][tx * 4 + j];
            #pragma unroll
            for (int i = 0; i < 4; ++i)
                #pragma unroll
                for (int j = 0; j < 4; ++j)
                    c[i][j] += a[i] * bb[j];
        }
        __syncthreads();
    }

    #pragma unroll
    for (int i = 0; i < 4; ++i) {
        const int gm = m0 + ty * 4 + i;
        if (gm >= Mdim) continue;
        #pragma unroll
        for (int j = 0; j < 4; ++j) {
            const int gn = n0 + tx * 4 + j;
            if (gn < N) C[(size_t)gm * ldc + gn] = c[i][j];
        }
    }
}

// ---------------------------------------------------------------------------
// Launcher
// ---------------------------------------------------------------------------
extern "C" void kernel_launch(void* const* d_in, const int* in_sizes, int n_in,
                              void* d_out, int out_size, void* d_ws, size_t ws_size,
                              hipStream_t stream) {
    const float* inputs = (const float*)d_in[0];
    // d_in[1] = initial state (zeros) — folded out
    const float* W_ih   = (const float*)d_in[2];
    const float* W_hh   = (const float*)d_in[3];
    const float* W_out  = (const float*)d_in[4];

    float* out    = (float*)d_out;                 // SEQ*IDIM
    float* states = out + (size_t)SEQ * IDIM;      // SEQ*H

    float* pre_in = (float*)d_ws;                  // SEQ*H fp32 (16.4 MB)

    // Tagged s-broadcast scratch in the outputs region of d_out (overwritten
    // by phase 2): 4 slots * 2048 words * 8 B = 64 KB. Harness 0xAA poison
    // gives tag 0xAAAAAAAA, never equal to a live tag (1..1000).
    unsigned long long* part = (unsigned long long*)out;

    (void)hipFuncSetAttribute((const void*)esn_recurrent,
                              hipFuncAttributeMaxDynamicSharedMemorySize,
                              LDS_BYTES);

    // Phase 0: pre_in[t][r] = sum_i X[t][i] * W_ih[r][i]
    gemm_abt<<<dim3(H / BN, (SEQ + BM - 1) / BM), 256, 0, stream>>>(
        inputs, IDIM, W_ih, IDIM, pre_in, H, SEQ, H, IDIM, 0, nullptr, nullptr);

    // Phase 1: persistent sequential recurrence (256 blocks x 1024 threads)
    {
        const float* whh_p = W_hh;
        const float* pin_p = pre_in;
        float* st_p = states;
        unsigned long long* part_p = part;
        void* args[] = { (void*)&whh_p, (void*)&pin_p, (void*)&st_p, (void*)&part_p };
        hipLaunchCooperativeKernel((const void*)esn_recurrent,
                                   dim3(256), dim3(1024), args, LDS_BYTES, stream);
    }

    // Phase 2: outputs[t][i] = sum_k ext[t][k] * W_out[i][k]
    gemm_abt<<<dim3((IDIM + BN - 1) / BN, (SEQ + BM - 1) / BM), 256, 0, stream>>>(
        nullptr, 0, W_out, 1 + IDIM + H, out, IDIM,
        SEQ, IDIM, 1 + IDIM + H, 1, inputs, states);
}

// Round 3
// 3846.033 us; speedup vs baseline: 1.6613x; 1.1372x over previous
//
#include <hip/hip_runtime.h>
#include <hip/hip_fp16.h>

#define SEQ  1000
#define IDIM 900
#define H    4096

// LDS carve-up for esn_recurrent (W_hh lives in REGISTERS):
//   s2   : uint[2][2048]  s[t] fp16 pairs, double-buffered = 16384 B
//   redf : float[16][5]   per-(row,colquad) partials       =   320 B
#define LDS_BYTES (16384 + 320)

typedef _Float16 h2_t __attribute__((ext_vector_type(2)));

__device__ __forceinline__ float fdot2(unsigned a, unsigned b, float c) {
#if __has_builtin(__builtin_amdgcn_fdot2)
    return __builtin_amdgcn_fdot2(__builtin_bit_cast(h2_t, a),
                                  __builtin_bit_cast(h2_t, b), c, false);
#else
    h2_t ha = __builtin_bit_cast(h2_t, a);
    h2_t hb = __builtin_bit_cast(h2_t, b);
    return c + (float)ha.x * (float)hb.x + (float)ha.y * (float)hb.y;
#endif
}

__device__ __forceinline__ float tanh_fast(float x) {
    float ax = __builtin_fabsf(x);
    float e  = __expf(-2.0f * ax);
    float t  = (1.0f - e) / (1.0f + e);
    return __builtin_copysignf(t, x);
}

// Bank swizzle on s2 dword indices: XOR bits [4:2] with bits [7:5].
__device__ __forceinline__ int swz2(int d) { return d ^ (((d >> 5) & 7) << 2); }

__device__ __forceinline__ uint4 pack8(float4 f0, float4 f1) {
    __half2 p; uint4 u;
    p = __floats2half2_rn(f0.x, f0.y); u.x = *(unsigned*)&p;
    p = __floats2half2_rn(f0.z, f0.w); u.y = *(unsigned*)&p;
    p = __floats2half2_rn(f1.x, f1.y); u.z = *(unsigned*)&p;
    p = __floats2half2_rn(f1.z, f1.w); u.w = *(unsigned*)&p;
    return u;
}

// ---------------------------------------------------------------------------
// Persistent recurrent kernel, round-9 (UNCHANGED, proven 2970 us):
// W_hh in registers, 256 blocks x 1024 threads, merged 7-shuffle butterfly,
// 2 barriers/step, 4-slot tagged global broadcast.
// ---------------------------------------------------------------------------
__global__ __launch_bounds__(1024, 4) void esn_recurrent(
    const float* __restrict__ Whh,            // H*H row-major fp32
    const float* __restrict__ pre_in,         // SEQ*H = X @ W_ih^T  (ws)
    float*       __restrict__ states,         // SEQ*H (inside d_out)
    unsigned long long* __restrict__ part)    // 4*2048 tagged words (d_out scratch)
{
    extern __shared__ char smem[];
    unsigned* s2   = (unsigned*)smem;               // [2][2048] swizzled
    float*    redf = (float*)(smem + 16384);        // [16][5]

    const int B    = blockIdx.x;       // owns rows [16B, +16)
    const int tid  = threadIdx.x;
    const int wave = tid >> 6;         // 0..15
    const int lane = tid & 63;
    const int h    = wave >> 2;        // row quad: rows 4h..4h+3 (of my 16)
    const int qd   = wave & 3;         // col quad: cols [1024qd, +1024)

    // ---- prologue first: publish s[0] for my rows (gates other blocks) ----
    if (wave == 0) {
        float s0 = 0.f;
        if (lane < 16) {
            s0 = tanh_fast(pre_in[(B << 4) + lane]);
            states[(B << 4) + lane] = s0;
        }
        float a = __shfl(s0, lane << 1);
        float b = __shfl(s0, (lane << 1) + 1);
        if (lane < 8) {
            __half2 p = __floats2half2_rn(a, b);
            unsigned long long wrd = (1ull << 32)
                                   | (unsigned long long)(*(unsigned*)&p);
            __hip_atomic_store(part + (B << 3) + lane, wrd,
                               __ATOMIC_RELAXED, __HIP_MEMORY_SCOPE_AGENT);
        }
    }

    // ---- load my 4x16 W_hh patch into registers (fp16 pairs, once) ----
    uint4 wa0, wb0, wa1, wb1, wa2, wb2, wa3, wb3;
    {
        const float* wsrc = Whh + ((size_t)((B << 4) + (h << 2))) * H
                          + (qd << 10) + (lane << 4);
        const float4* r0 = (const float4*)(wsrc);
        const float4* r1 = (const float4*)(wsrc + H);
        const float4* r2 = (const float4*)(wsrc + 2 * H);
        const float4* r3 = (const float4*)(wsrc + 3 * H);
        wa0 = pack8(r0[0], r0[1]); wb0 = pack8(r0[2], r0[3]);
        wa1 = pack8(r1[0], r1[1]); wb1 = pack8(r1[2], r1[3]);
        wa2 = pack8(r2[0], r2[1]); wb2 = pack8(r2[2], r2[3]);
        wa3 = pack8(r3[0], r3[1]); wb3 = pack8(r3[2], r3[3]);
    }

    for (int t = 0; t < SEQ - 1; ++t) {
        float pv = 0.f;
        if (tid < 16) pv = pre_in[(size_t)(t + 1) * H + (B << 4) + tid];

        // ---- A. poll s[t] (slot t&3, tag t+1) ----
        {
            const unsigned long long* pb = part + ((size_t)(t & 3) << 11) + (tid << 1);
            const unsigned want = (unsigned)(t + 1);
            unsigned long long v0, v1;
            for (;;) {
                v0 = __hip_atomic_load(pb,     __ATOMIC_RELAXED, __HIP_MEMORY_SCOPE_AGENT);
                v1 = __hip_atomic_load(pb + 1, __ATOMIC_RELAXED, __HIP_MEMORY_SCOPE_AGENT);
                if ((unsigned)(v0 >> 32) == want && (unsigned)(v1 >> 32) == want) break;
                __builtin_amdgcn_s_sleep(1);
            }
            uint2 w; w.x = (unsigned)v0; w.y = (unsigned)v1;
            *(uint2*)(s2 + ((t & 1) << 11) + swz2(tid << 1)) = w;
        }
        __syncthreads();   // barrier A

        // ---- B. compute rows 4h..4h+3 x cols [1024qd + 16*lane, +16) ----
        const unsigned* sb = s2 + ((t & 1) << 11);
        const int cb = (qd << 9) + (lane << 3);
        uint4 sa = *(const uint4*)(sb + swz2(cb));
        uint4 sc = *(const uint4*)(sb + swz2(cb + 4));

        float a0 = 0.f, a1 = 0.f, a2 = 0.f, a3 = 0.f;
        a0 = fdot2(wa0.x, sa.x, a0); a0 = fdot2(wa0.y, sa.y, a0);
        a0 = fdot2(wa0.z, sa.z, a0); a0 = fdot2(wa0.w, sa.w, a0);
        a0 = fdot2(wb0.x, sc.x, a0); a0 = fdot2(wb0.y, sc.y, a0);
        a0 = fdot2(wb0.z, sc.z, a0); a0 = fdot2(wb0.w, sc.w, a0);
        a1 = fdot2(wa1.x, sa.x, a1); a1 = fdot2(wa1.y, sa.y, a1);
        a1 = fdot2(wa1.z, sa.z, a1); a1 = fdot2(wa1.w, sa.w, a1);
        a1 = fdot2(wb1.x, sc.x, a1); a1 = fdot2(wb1.y, sc.y, a1);
        a1 = fdot2(wb1.z, sc.z, a1); a1 = fdot2(wb1.w, sc.w, a1);
        a2 = fdot2(wa2.x, sa.x, a2); a2 = fdot2(wa2.y, sa.y, a2);
        a2 = fdot2(wa2.z, sa.z, a2); a2 = fdot2(wa2.w, sa.w, a2);
        a2 = fdot2(wb2.x, sc.x, a2); a2 = fdot2(wb2.y, sc.y, a2);
        a2 = fdot2(wb2.z, sc.z, a2); a2 = fdot2(wb2.w, sc.w, a2);
        a3 = fdot2(wa3.x, sa.x, a3); a3 = fdot2(wa3.y, sa.y, a3);
        a3 = fdot2(wa3.z, sa.z, a3); a3 = fdot2(wa3.w, sa.w, a3);
        a3 = fdot2(wb3.x, sc.x, a3); a3 = fdot2(wb3.y, sc.y, a3);
        a3 = fdot2(wb3.z, sc.z, a3); a3 = fdot2(wb3.w, sc.w, a3);

        // ---- merged butterfly: 7 shuffles ----
        float y0 = (lane & 1) ? a0 : a1;
        float x  = (lane & 1) ? a1 : a0;
        x += __shfl_xor(y0, 1);
        float y1 = (lane & 1) ? a2 : a3;
        float z  = (lane & 1) ? a3 : a2;
        z += __shfl_xor(y1, 1);
        float y2 = (lane & 2) ? x : z;
        float u  = (lane & 2) ? z : x;
        u += __shfl_xor(y2, 2);
        u += __shfl_xor(u, 4);
        u += __shfl_xor(u, 8);
        u += __shfl_xor(u, 16);
        u += __shfl_xor(u, 32);

        if (lane < 4) redf[((h << 2) + lane) * 5 + qd] = u;
        __syncthreads();   // barrier B

        // ---- C. finalize (wave 0 only) ----
        if (wave == 0) {
            float sf = 0.f;
            if (lane < 16) {
                const float* rf = redf + lane * 5;
                sf = tanh_fast(rf[0] + rf[1] + rf[2] + rf[3] + pv);
                states[(size_t)(t + 1) * H + (B << 4) + lane] = sf;
            }
            float a = __shfl(sf, lane << 1);
            float b = __shfl(sf, (lane << 1) + 1);
            if (lane < 8) {
                __half2 p = __floats2half2_rn(a, b);
                unsigned long long wrd = ((unsigned long long)(unsigned)(t + 2) << 32)
                                       | (unsigned long long)(*(unsigned*)&p);
                __hip_atomic_store(part + ((size_t)((t + 1) & 3) << 11) + (B << 3) + lane,
                                   wrd, __ATOMIC_RELAXED, __HIP_MEMORY_SCOPE_AGENT);
            }
        }
    }
}

// ---------------------------------------------------------------------------
// Generic fp32 tiled GEMM:  C[MxN] = A[MxK] * B[NxK]^T   (both row-major)
// mode 0: A plain (lda). mode 1: virtual ext row t: [1, X[t], S[t]].
// Round-10: +4 padding (16B-aligned rows) and float4 LDS fragment reads.
// ---------------------------------------------------------------------------
#define BM 64
#define BN 64
#define BK 32

__global__ __launch_bounds__(256) void gemm_abt(
    const float* __restrict__ A, int lda,
    const float* __restrict__ B, int ldb,
    float*       __restrict__ C, int ldc,
    int Mdim, int N, int K, int mode,
    const float* __restrict__ X, const float* __restrict__ S)
{
    __shared__ __align__(16) float As[BK][BM + 4];
    __shared__ __align__(16) float Bs[BK][BN + 4];

    const int tid = threadIdx.x;
    const int n0  = blockIdx.x * BN;
    const int m0  = blockIdx.y * BM;
    const int tx  = tid & 15;
    const int ty  = tid >> 4;

    float c[4][4] = {};

    for (int k0 = 0; k0 < K; k0 += BK) {
        #pragma unroll
        for (int p = 0; p < 8; ++p) {
            const int idx = tid + p * 256;
            const int mm  = idx >> 5;
            const int kk  = idx & 31;
            const int gk  = k0 + kk;

            float av = 0.f;
            const int gm = m0 + mm;
            if (gm < Mdim && gk < K) {
                if (mode == 0) {
                    av = A[(size_t)gm * lda + gk];
                } else {
                    if (gk == 0)          av = 1.0f;
                    else if (gk <= IDIM)  av = X[(size_t)gm * IDIM + (gk - 1)];
                    else                  av = S[(size_t)gm * H + (gk - 1 - IDIM)];
                }
            }
            As[kk][mm] = av;

            float bv = 0.f;
            const int gn = n0 + mm;
            if (gn < N && gk < K) bv = B[(size_t)gn * ldb + gk];
            Bs[kk][mm] = bv;
        }
        __syncthreads();

        #pragma unroll
        for (int kk = 0; kk < BK; ++kk) {
            float4 a = *(const float4*)&As[kk][ty * 4];
            float4 b = *(const float4*)&Bs[kk][tx * 4];
            float av[4] = {a.x, a.y, a.z, a.w};
            float bv[4] = {b.x, b.y, b.z, b.w};
            #pragma unroll
            for (int i = 0; i < 4; ++i)
                #pragma unroll
                for (int j = 0; j < 4; ++j)
                    c[i][j] += av[i] * bv[j];
        }
        __syncthreads();
    }

    #pragma unroll
    for (int i = 0; i < 4; ++i) {
        const int gm = m0 + ty * 4 + i;
        if (gm >= Mdim) continue;
        #pragma unroll
        for (int j = 0; j < 4; ++j) {
            const int gn = n0 + tx * 4 + j;
            if (gn < N) C[(size_t)gm * ldc + gn] = c[i][j];
        }
    }
}

// ---------------------------------------------------------------------------
// Split-K GEMM for phase 2 (mode-1 virtual A only):
//   Cp[z][M][N] partial over K-slice z. Grid (N/BN, M/BM, 4).
// Region-uniform staging: pure-S tiles (the vast majority, k0 >= 901) skip
// the per-element 3-way branch.
// ---------------------------------------------------------------------------
#define KSLICE 1280   // 40 tiles of 32; slice 3 gets the 1157-tail

__global__ __launch_bounds__(256) void gemm_splitk(
    const float* __restrict__ Bw, int ldb,
    float*       __restrict__ Cp,            // 4 partials, stride M*N
    int Mdim, int N, int K,
    const float* __restrict__ X, const float* __restrict__ S)
{
    __shared__ __align__(16) float As[BK][BM + 4];
    __shared__ __align__(16) float Bs[BK][BN + 4];

    const int tid = threadIdx.x;
    const int n0  = blockIdx.x * BN;
    const int m0  = blockIdx.y * BM;
    const int z   = blockIdx.z;
    const int tx  = tid & 15;
    const int ty  = tid >> 4;

    const int kbeg = z * KSLICE;
    const int kend = min(K, kbeg + KSLICE);

    float c[4][4] = {};

    for (int k0 = kbeg; k0 < kend; k0 += BK) {
        const bool pureS = (k0 >= IDIM + 1) && (k0 + BK <= kend);
        const bool pureX = (k0 > 0) && (k0 + BK <= IDIM + 1);
        #pragma unroll
        for (int p = 0; p < 8; ++p) {
            const int idx = tid + p * 256;
            const int mm  = idx >> 5;
            const int kk  = idx & 31;
            const int gk  = k0 + kk;
            const int gm  = m0 + mm;

            float av = 0.f;
            if (gm < Mdim) {
                if (pureS)      av = S[(size_t)gm * H + (gk - 1 - IDIM)];
                else if (pureX) av = X[(size_t)gm * IDIM + (gk - 1)];
                else if (gk < kend) {
                    if (gk == 0)          av = 1.0f;
                    else if (gk <= IDIM)  av = X[(size_t)gm * IDIM + (gk - 1)];
                    else                  av = S[(size_t)gm * H + (gk - 1 - IDIM)];
                }
            }
            As[kk][mm] = av;

            float bv = 0.f;
            const int gn = n0 + mm;
            if (gn < N && gk < kend) bv = Bw[(size_t)gn * ldb + gk];
            Bs[kk][mm] = bv;
        }
        __syncthreads();

        #pragma unroll
        for (int kk = 0; kk < BK; ++kk) {
            float4 a = *(const float4*)&As[kk][ty * 4];
            float4 b = *(const float4*)&Bs[kk][tx * 4];
            float av[4] = {a.x, a.y, a.z, a.w};
            float bv[4] = {b.x, b.y, b.z, b.w};
            #pragma unroll
            for (int i = 0; i < 4; ++i)
                #pragma unroll
                for (int j = 0; j < 4; ++j)
                    c[i][j] += av[i] * bv[j];
        }
        __syncthreads();
    }

    float* Cz = Cp + (size_t)z * ((size_t)SEQ * IDIM);
    #pragma unroll
    for (int i = 0; i < 4; ++i) {
        const int gm = m0 + ty * 4 + i;
        if (gm >= Mdim) continue;
        #pragma unroll
        for (int j = 0; j < 4; ++j) {
            const int gn = n0 + tx * 4 + j;
            if (gn < N) Cz[(size_t)gm * N + gn] = c[i][j];
        }
    }
}

// out[i] = sum of 4 split-K partials (SEQ*IDIM floats, /4 exact)
__global__ __launch_bounds__(256) void reduce4(
    const float4* __restrict__ p, float4* __restrict__ o, int n4)
{
    const size_t stride = (size_t)SEQ * IDIM / 4;
    for (int i = blockIdx.x * 256 + threadIdx.x; i < n4; i += gridDim.x * 256) {
        float4 a = p[i];
        float4 b = p[i + stride];
        float4 c = p[i + 2 * stride];
        float4 d = p[i + 3 * stride];
        float4 r;
        r.x = a.x + b.x + c.x + d.x;
        r.y = a.y + b.y + c.y + d.y;
        r.z = a.z + b.z + c.z + d.z;
        r.w = a.w + b.w + c.w + d.w;
        o[i] = r;
    }
}

// ---------------------------------------------------------------------------
// Launcher
// ---------------------------------------------------------------------------
extern "C" void kernel_launch(void* const* d_in, const int* in_sizes, int n_in,
                              void* d_out, int out_size, void* d_ws, size_t ws_size,
                              hipStream_t stream) {
    const float* inputs = (const float*)d_in[0];
    // d_in[1] = initial state (zeros) — folded out
    const float* W_ih   = (const float*)d_in[2];
    const float* W_hh   = (const float*)d_in[3];
    const float* W_out  = (const float*)d_in[4];

    float* out    = (float*)d_out;                 // SEQ*IDIM
    float* states = out + (size_t)SEQ * IDIM;      // SEQ*H

    float* pre_in = (float*)d_ws;                  // SEQ*H fp32 (16.4 MB)
    float* cpart  = pre_in + (size_t)SEQ * H;      // 4 * SEQ*IDIM fp32 (14.4 MB)

    const size_t ws_needed = ((size_t)SEQ * H + 4ull * SEQ * IDIM) * sizeof(float);
    const bool   use_splitk = (ws_size >= ws_needed);

    // Tagged s-broadcast scratch in the outputs region of d_out (overwritten
    // by phase 2): 4 slots * 2048 words * 8 B = 64 KB. Harness 0xAA poison
    // gives tag 0xAAAAAAAA, never equal to a live tag (1..1000).
    unsigned long long* part = (unsigned long long*)out;

    (void)hipFuncSetAttribute((const void*)esn_recurrent,
                              hipFuncAttributeMaxDynamicSharedMemorySize,
                              LDS_BYTES);

    // Phase 0: pre_in[t][r] = sum_i X[t][i] * W_ih[r][i]
    gemm_abt<<<dim3(H / BN, (SEQ + BM - 1) / BM), 256, 0, stream>>>(
        inputs, IDIM, W_ih, IDIM, pre_in, H, SEQ, H, IDIM, 0, nullptr, nullptr);

    // Phase 1: persistent sequential recurrence (256 blocks x 1024 threads)
    {
        const float* whh_p = W_hh;
        const float* pin_p = pre_in;
        float* st_p = states;
        unsigned long long* part_p = part;
        void* args[] = { (void*)&whh_p, (void*)&pin_p, (void*)&st_p, (void*)&part_p };
        hipLaunchCooperativeKernel((const void*)esn_recurrent,
                                   dim3(256), dim3(1024), args, LDS_BYTES, stream);
    }

    // Phase 2: outputs[t][i] = sum_k ext[t][k] * W_out[i][k]
    if (use_splitk) {
        gemm_splitk<<<dim3((IDIM + BN - 1) / BN, (SEQ + BM - 1) / BM, 4),
                      256, 0, stream>>>(
            W_out, 1 + IDIM + H, cpart, SEQ, IDIM, 1 + IDIM + H, inputs, states);
        const int n4 = SEQ * IDIM / 4;
        reduce4<<<dim3(880), 256, 0, stream>>>(
            (const float4*)cpart, (float4*)out, n4);
    } else {
        gemm_abt<<<dim3((IDIM + BN - 1) / BN, (SEQ + BM - 1) / BM), 256, 0, stream>>>(
            nullptr, 0, W_out, 1 + IDIM + H, out, IDIM,
            SEQ, IDIM, 1 + IDIM + H, 1, inputs, states);
    }
}